// Round 2
// baseline (391.934 us; speedup 1.0000x reference)
//
#include <hip/hip_runtime.h>

// FocalLoss (RetinaNet-style) on MI355X.
// Inputs (fp32): classifications (8,49104,90), regressions (8,49104,4),
//                anchors (1,49104,4), annotations (8,32,5)
// Output: 2 fp32 scalars (clf_loss, reg_loss).
//
// Strategy: default contribution of every clf element is the NEGATIVE focal
// term (tgt==0). A branch-free elementwise kernel sums x^2*log2(1-x) over all
// B*A*C elements; the match kernel applies sparse corrections for matched
// anchors (one positive element each) and ignored anchors (whole row zeroed).

namespace {
constexpr int B_N = 8;
constexpr int A_N = 49104;
constexpr int C_N = 90;
constexpr int M_N = 32;
constexpr float EPSF   = 1e-4f;
constexpr float ACCEPT = 0.5f;
constexpr float REJECT = 0.4f;
constexpr float SL1R   = 9.0f;
constexpr float CLFW   = 1.0f;
constexpr float REGW   = 50.0f;
constexpr float LN2    = 0.69314718055994530942f;

__device__ __forceinline__ float clampx(float x) {
    return fminf(fmaxf(x, EPSF), 1.0f - EPSF);
}
__device__ __forceinline__ float neg_term(float x) {   // tgt==0 focal term
    x = clampx(x);
    return 0.75f * x * x * (-__logf(1.0f - x));
}
__device__ __forceinline__ float pos_term(float x) {   // tgt==1 focal term
    x = clampx(x);
    float o = 1.0f - x;
    return 0.25f * o * o * (-__logf(x));
}
} // namespace

// ---------------- kernel 1: match + reg loss + clf corrections ----------------
// grid (ceil(A/256), B), block 256. One thread per anchor.
__global__ void match_kernel(const float* __restrict__ anchors,
                             const float* __restrict__ reg,
                             const float* __restrict__ ann,
                             const float* __restrict__ clf,
                             int*   __restrict__ nm,        // [B]
                             float* __restrict__ reg_sum,   // [B]
                             float* __restrict__ corr_sum)  // [B]
{
    __shared__ float sann[M_N * 5];
    const int b   = blockIdx.y;
    const int tid = threadIdx.x;
    if (tid < M_N * 5) sann[tid] = ann[b * M_N * 5 + tid];
    __syncthreads();

    const int i = blockIdx.x * blockDim.x + tid;
    int   cnt  = 0;
    float rsum = 0.0f;
    float corr = 0.0f;

    if (i < A_N) {
        const float4 av = ((const float4*)anchors)[i];
        const float ay1 = av.x, ax1 = av.y, ay2 = av.z, ax2 = av.w;
        const float aw = ax2 - ax1, ah = ay2 - ay1;
        const float aarea = aw * ah;

        float best = -3.4e38f;
        int   arg  = 0;
        #pragma unroll 8
        for (int j = 0; j < M_N; ++j) {
            const float bx1 = sann[j*5+0], by1 = sann[j*5+1];
            const float bx2 = sann[j*5+2], by2 = sann[j*5+3];
            const float lb  = sann[j*5+4];
            float iw = fminf(ax2, bx2) - fmaxf(ax1, bx1); iw = fmaxf(iw, 0.0f);
            float ih = fminf(ay2, by2) - fmaxf(ay1, by1); ih = fmaxf(ih, 0.0f);
            const float inter = iw * ih;
            const float barea = (bx2 - bx1) * (by2 - by1);
            const float uni   = fmaxf(aarea + barea - inter, 1e-8f);
            float iou = inter / uni;
            if (lb == -1.0f) iou = -1.0f;
            if (iou > best) { best = iou; arg = j; } // first-occurrence argmax
        }

        const bool matched   = best > ACCEPT;
        const bool unmatched = best < REJECT;
        const float* __restrict__ row = clf + (size_t)(b * A_N + i) * C_N;

        if (matched) {
            const int s = (int)sann[arg*5+4] - 1;   // class index 0..89
            cnt = 1;
            // clf correction: replace neg term with pos term at class s
            const float x = row[s];
            corr += pos_term(x) - neg_term(x);
            // regression loss from matched box
            const float bx1 = sann[arg*5+0], by1 = sann[arg*5+1];
            const float bx2 = sann[arg*5+2], by2 = sann[arg*5+3];
            const float gwr = bx2 - bx1, ghr = by2 - by1;
            const float gcx = bx1 + 0.5f * gwr, gcy = by1 + 0.5f * ghr;
            const float gw  = fmaxf(gwr, 1.0f), gh = fmaxf(ghr, 1.0f);
            const float acx = ax1 + 0.5f * aw, acy = ay1 + 0.5f * ah;
            const float t0 = (gcy - acy) / ah;
            const float t1 = (gcx - acx) / aw;
            const float t2 = __logf(gh / ah);
            const float t3 = __logf(gw / aw);
            const float4 rv = ((const float4*)reg)[b * A_N + i];
            float d;
            d = fabsf(SL1R * (rv.x - t0)); rsum += (d < 1.0f) ? 0.5f*d*d : d - 0.5f;
            d = fabsf(SL1R * (rv.y - t1)); rsum += (d < 1.0f) ? 0.5f*d*d : d - 0.5f;
            d = fabsf(SL1R * (rv.z - t2)); rsum += (d < 1.0f) ? 0.5f*d*d : d - 0.5f;
            d = fabsf(SL1R * (rv.w - t3)); rsum += (d < 1.0f) ? 0.5f*d*d : d - 0.5f;
        } else if (!unmatched) {
            // ignored anchor: remove the whole row's neg contribution
            // row byte offset = (b*A+i)*360, always 8B-aligned -> float2 loads
            const float2* __restrict__ r2 = (const float2*)row;
            float rs = 0.0f;
            #pragma unroll
            for (int c = 0; c < C_N / 2; ++c) {
                const float2 u = r2[c];
                rs += neg_term(u.x) + neg_term(u.y);
            }
            corr -= rs;
        }
    }

    // wave(64) reduce, one atomic per wave
    #pragma unroll
    for (int off = 32; off > 0; off >>= 1) {
        cnt  += __shfl_down(cnt,  off);
        rsum += __shfl_down(rsum, off);
        corr += __shfl_down(corr, off);
    }
    if ((tid & 63) == 0) {
        if (cnt)         atomicAdd(&nm[b], cnt);
        if (rsum != 0.f) atomicAdd(&reg_sum[b], rsum);
        if (corr != 0.f) atomicAdd(&corr_sum[b], corr);
    }
}

// ---------------- kernel 2: branch-free base focal sum ----------------
// Accumulates sum of x^2 * log2(1-x) over one image (scaled by -0.75*ln2 in
// finalize). grid (256, B), block 256; two independent float4 streams per
// thread, 2-deep software pipeline.
__global__ void base_kernel(const float* __restrict__ clf,
                            float*       __restrict__ base_sum)  // [B]
{
    constexpr unsigned HALF = (unsigned)(A_N * C_N) / 8u; // 552420
    const int b = blockIdx.y;
    const float4* __restrict__ p = (const float4*)(clf + (size_t)b * A_N * C_N);

    float sum = 0.0f;
    const unsigned stride = gridDim.x * blockDim.x;
    unsigned f = blockIdx.x * blockDim.x + threadIdx.x;

    auto work4 = [](float4 v) -> float {
        float s = 0.0f;
        {
            float x = clampx(v.x); s += x * x * __log2f(1.0f - x);
        }
        {
            float x = clampx(v.y); s += x * x * __log2f(1.0f - x);
        }
        {
            float x = clampx(v.z); s += x * x * __log2f(1.0f - x);
        }
        {
            float x = clampx(v.w); s += x * x * __log2f(1.0f - x);
        }
        return s;
    };

    if (f < HALF) {
        float4 v0 = p[f];
        float4 v1 = p[f + HALF];
        for (unsigned nf = f + stride; nf < HALF; nf += stride) {
            const float4 w0 = p[nf];
            const float4 w1 = p[nf + HALF];
            sum += work4(v0) + work4(v1);
            v0 = w0; v1 = w1;
        }
        sum += work4(v0) + work4(v1);
    }

    #pragma unroll
    for (int off = 32; off > 0; off >>= 1) sum += __shfl_down(sum, off);
    if ((threadIdx.x & 63) == 0) atomicAdd(&base_sum[b], sum);
}

// ---------------- kernel 3: finalize ----------------
__global__ void finalize_kernel(const int*   __restrict__ nm,
                                const float* __restrict__ base_sum,
                                const float* __restrict__ corr_sum,
                                const float* __restrict__ reg_sum,
                                float*       __restrict__ out)
{
    if (threadIdx.x == 0 && blockIdx.x == 0) {
        float cl = 0.0f, rl = 0.0f;
        for (int b = 0; b < B_N; ++b) {
            const int n = nm[b];
            const float clf_total = -0.75f * LN2 * base_sum[b] + corr_sum[b];
            cl += clf_total / (float)(n > 1 ? n : 1);
            if (n > 0) rl += reg_sum[b] / (float)(4 * n);
        }
        out[0] = CLFW * (cl / (float)B_N);
        out[1] = REGW * (rl / (float)B_N);
    }
}

extern "C" void kernel_launch(void* const* d_in, const int* in_sizes, int n_in,
                              void* d_out, int out_size, void* d_ws, size_t ws_size,
                              hipStream_t stream) {
    const float* clf     = (const float*)d_in[0];
    const float* reg     = (const float*)d_in[1];
    const float* anchors = (const float*)d_in[2];
    const float* ann     = (const float*)d_in[3];
    float* out = (float*)d_out;

    char* ws = (char*)d_ws;
    int*   nm       = (int*)(ws + 0);     // 8 ints
    float* base_sum = (float*)(ws + 64);  // 8 floats
    float* corr_sum = (float*)(ws + 128); // 8 floats
    float* reg_sum  = (float*)(ws + 192); // 8 floats

    // zero the accumulators (ws is poisoned 0xAA before each call)
    hipMemsetAsync(d_ws, 0, 256, stream);

    {
        dim3 grid((A_N + 255) / 256, B_N);
        match_kernel<<<grid, 256, 0, stream>>>(anchors, reg, ann, clf,
                                               nm, reg_sum, corr_sum);
    }
    {
        dim3 grid(256, B_N);  // 2048 blocks x 256 threads
        base_kernel<<<grid, 256, 0, stream>>>(clf, base_sum);
    }
    finalize_kernel<<<1, 64, 0, stream>>>(nm, base_sum, corr_sum, reg_sum, out);
}

// Round 3
// 238.641 us; speedup vs baseline: 1.6424x; 1.6424x over previous
//
#include <hip/hip_runtime.h>

// FocalLoss (RetinaNet-style) on MI355X.
// Inputs (fp32): classifications (8,49104,90), regressions (8,49104,4),
//                anchors (1,49104,4), annotations (8,32,5)
// Output: 2 fp32 scalars (clf_loss, reg_loss).
//
// R3: NO global atomics on the hot path (R1/R2 showed 8192 same-line
// atomicAdds serialize to ~140us). Every block writes its partial to a
// unique d_ws slot; finalize reduces. Base kernel: 4 independent float4
// streams/thread + med3 clamp.

namespace {
constexpr int B_N = 8;
constexpr int A_N = 49104;
constexpr int C_N = 90;
constexpr int M_N = 32;
constexpr float EPSF   = 1e-4f;
constexpr float ACCEPT = 0.5f;
constexpr float REJECT = 0.4f;
constexpr float SL1R   = 9.0f;
constexpr float CLFW   = 1.0f;
constexpr float REGW   = 50.0f;
constexpr float LN2    = 0.69314718055994530942f;

constexpr int MATCH_BX = 192;   // ceil(49104/256)
constexpr int BASE_BX  = 256;

// ws layout (floats):
//   basep : [B][BASE_BX]          offset 0        (2048 floats)
//   matchp: [B][MATCH_BX] float4  offset 2048     (cnt, rsum, corr, pad)
constexpr int BASEP_OFF  = 0;
constexpr int MATCHP_OFF = 2048;

__device__ __forceinline__ float clampx(float x) {
    return __builtin_amdgcn_fmed3f(x, EPSF, 1.0f - EPSF);
}
__device__ __forceinline__ float neg_term(float x) {   // tgt==0 focal term
    x = clampx(x);
    return 0.75f * x * x * (-__logf(1.0f - x));
}
__device__ __forceinline__ float pos_term(float x) {   // tgt==1 focal term
    x = clampx(x);
    float o = 1.0f - x;
    return 0.25f * o * o * (-__logf(x));
}
} // namespace

// ---------------- kernel 1: match + reg loss + clf corrections ----------------
// grid (MATCH_BX, B), block 256. One thread per anchor.
__global__ void match_kernel(const float* __restrict__ anchors,
                             const float* __restrict__ reg,
                             const float* __restrict__ ann,
                             const float* __restrict__ clf,
                             float* __restrict__ ws)
{
    __shared__ float sann[M_N * 5];
    __shared__ float sred[4][3];
    const int b   = blockIdx.y;
    const int tid = threadIdx.x;
    if (tid < M_N * 5) sann[tid] = ann[b * M_N * 5 + tid];
    __syncthreads();

    const int i = blockIdx.x * blockDim.x + tid;
    float cnt  = 0.0f;
    float rsum = 0.0f;
    float corr = 0.0f;

    if (i < A_N) {
        const float4 av = ((const float4*)anchors)[i];
        const float ay1 = av.x, ax1 = av.y, ay2 = av.z, ax2 = av.w;
        const float aw = ax2 - ax1, ah = ay2 - ay1;
        const float aarea = aw * ah;

        float best = -3.4e38f;
        int   arg  = 0;
        #pragma unroll 8
        for (int j = 0; j < M_N; ++j) {
            const float bx1 = sann[j*5+0], by1 = sann[j*5+1];
            const float bx2 = sann[j*5+2], by2 = sann[j*5+3];
            const float lb  = sann[j*5+4];
            float iw = fminf(ax2, bx2) - fmaxf(ax1, bx1); iw = fmaxf(iw, 0.0f);
            float ih = fminf(ay2, by2) - fmaxf(ay1, by1); ih = fmaxf(ih, 0.0f);
            const float inter = iw * ih;
            const float barea = (bx2 - bx1) * (by2 - by1);
            const float uni   = fmaxf(aarea + barea - inter, 1e-8f);
            float iou = inter / uni;
            if (lb == -1.0f) iou = -1.0f;
            if (iou > best) { best = iou; arg = j; } // first-occurrence argmax
        }

        const bool matched   = best > ACCEPT;
        const bool unmatched = best < REJECT;
        const float* __restrict__ row = clf + (size_t)(b * A_N + i) * C_N;

        if (matched) {
            const int s = (int)sann[arg*5+4] - 1;   // class index 0..89
            cnt = 1.0f;
            // clf correction: replace neg term with pos term at class s
            const float x = row[s];
            corr += pos_term(x) - neg_term(x);
            // regression loss from matched box
            const float bx1 = sann[arg*5+0], by1 = sann[arg*5+1];
            const float bx2 = sann[arg*5+2], by2 = sann[arg*5+3];
            const float gwr = bx2 - bx1, ghr = by2 - by1;
            const float gcx = bx1 + 0.5f * gwr, gcy = by1 + 0.5f * ghr;
            const float gw  = fmaxf(gwr, 1.0f), gh = fmaxf(ghr, 1.0f);
            const float acx = ax1 + 0.5f * aw, acy = ay1 + 0.5f * ah;
            const float t0 = (gcy - acy) / ah;
            const float t1 = (gcx - acx) / aw;
            const float t2 = __logf(gh / ah);
            const float t3 = __logf(gw / aw);
            const float4 rv = ((const float4*)reg)[b * A_N + i];
            float d;
            d = fabsf(SL1R * (rv.x - t0)); rsum += (d < 1.0f) ? 0.5f*d*d : d - 0.5f;
            d = fabsf(SL1R * (rv.y - t1)); rsum += (d < 1.0f) ? 0.5f*d*d : d - 0.5f;
            d = fabsf(SL1R * (rv.z - t2)); rsum += (d < 1.0f) ? 0.5f*d*d : d - 0.5f;
            d = fabsf(SL1R * (rv.w - t3)); rsum += (d < 1.0f) ? 0.5f*d*d : d - 0.5f;
        } else if (!unmatched) {
            // ignored anchor: remove the whole row's neg contribution
            const float2* __restrict__ r2 = (const float2*)row;
            float rs = 0.0f;
            #pragma unroll
            for (int c = 0; c < C_N / 2; ++c) {
                const float2 u = r2[c];
                rs += neg_term(u.x) + neg_term(u.y);
            }
            corr -= rs;
        }
    }

    // wave reduce, then block reduce in LDS, one ws write per block
    #pragma unroll
    for (int off = 32; off > 0; off >>= 1) {
        cnt  += __shfl_down(cnt,  off);
        rsum += __shfl_down(rsum, off);
        corr += __shfl_down(corr, off);
    }
    const int wid = tid >> 6;
    if ((tid & 63) == 0) {
        sred[wid][0] = cnt; sred[wid][1] = rsum; sred[wid][2] = corr;
    }
    __syncthreads();
    if (tid == 0) {
        float c = 0.f, r = 0.f, k = 0.f;
        #pragma unroll
        for (int w = 0; w < 4; ++w) { c += sred[w][0]; r += sred[w][1]; k += sred[w][2]; }
        float4* mp = (float4*)(ws + MATCHP_OFF);
        mp[b * MATCH_BX + blockIdx.x] = make_float4(c, r, k, 0.0f);
    }
}

// ---------------- kernel 2: branch-free base focal sum ----------------
// Accumulates sum of x^2 * log2(1-x) (scaled by -0.75*ln2 in finalize).
// grid (BASE_BX, B), block 256; 4 independent float4 streams per thread.
__global__ void base_kernel(const float* __restrict__ clf,
                            float*       __restrict__ ws)
{
    constexpr unsigned TOT_F4 = (unsigned)(A_N * C_N) / 4u;  // 1,104,840
    constexpr unsigned Q      = TOT_F4 / 4u;                 // 276,210 (exact)
    const int b = blockIdx.y;
    const float4* __restrict__ p = (const float4*)(clf + (size_t)b * A_N * C_N);

    float sum = 0.0f;
    const unsigned stride = gridDim.x * blockDim.x;   // 65536

    auto work4 = [](float4 v) -> float {
        float s = 0.0f;
        float x0 = clampx(v.x), x1 = clampx(v.y), x2 = clampx(v.z), x3 = clampx(v.w);
        s = fmaf(x0 * x0, __log2f(1.0f - x0), s);
        s = fmaf(x1 * x1, __log2f(1.0f - x1), s);
        s = fmaf(x2 * x2, __log2f(1.0f - x2), s);
        s = fmaf(x3 * x3, __log2f(1.0f - x3), s);
        return s;
    };

    for (unsigned f = blockIdx.x * blockDim.x + threadIdx.x; f < Q; f += stride) {
        const float4 v0 = p[f];
        const float4 v1 = p[f + Q];
        const float4 v2 = p[f + 2u * Q];
        const float4 v3 = p[f + 3u * Q];
        sum += work4(v0) + work4(v1) + work4(v2) + work4(v3);
    }

    __shared__ float sred[4];
    #pragma unroll
    for (int off = 32; off > 0; off >>= 1) sum += __shfl_down(sum, off);
    const int tid = threadIdx.x;
    if ((tid & 63) == 0) sred[tid >> 6] = sum;
    __syncthreads();
    if (tid == 0) {
        ws[BASEP_OFF + b * BASE_BX + blockIdx.x] =
            sred[0] + sred[1] + sred[2] + sred[3];
    }
}

// ---------------- kernel 3: finalize ----------------
// 1 block, 256 threads: threads b*32..b*32+31 reduce image b's partials.
__global__ void finalize_kernel(const float* __restrict__ ws,
                                float*       __restrict__ out)
{
    __shared__ float s_base[B_N], s_cnt[B_N], s_rsum[B_N], s_corr[B_N];
    const int tid = threadIdx.x;
    const int b   = tid >> 5;
    const int j   = tid & 31;

    float base = 0.f, cnt = 0.f, rsum = 0.f, corr = 0.f;
    #pragma unroll
    for (int k = 0; k < BASE_BX / 32; ++k)          // 8 slots
        base += ws[BASEP_OFF + b * BASE_BX + j + 32 * k];
    const float4* mp = (const float4*)(ws + MATCHP_OFF);
    #pragma unroll
    for (int k = 0; k < MATCH_BX / 32; ++k) {       // 6 slots
        const float4 m = mp[b * MATCH_BX + j + 32 * k];
        cnt += m.x; rsum += m.y; corr += m.z;
    }
    #pragma unroll
    for (int off = 16; off > 0; off >>= 1) {
        base += __shfl_down(base, off, 32);
        cnt  += __shfl_down(cnt,  off, 32);
        rsum += __shfl_down(rsum, off, 32);
        corr += __shfl_down(corr, off, 32);
    }
    if (j == 0) { s_base[b] = base; s_cnt[b] = cnt; s_rsum[b] = rsum; s_corr[b] = corr; }
    __syncthreads();
    if (tid == 0) {
        float cl = 0.0f, rl = 0.0f;
        #pragma unroll
        for (int bb = 0; bb < B_N; ++bb) {
            const float n = s_cnt[bb];
            const float clf_total = -0.75f * LN2 * s_base[bb] + s_corr[bb];
            cl += clf_total / fmaxf(1.0f, n);
            if (n > 0.0f) rl += s_rsum[bb] / (4.0f * n);
        }
        out[0] = CLFW * (cl / (float)B_N);
        out[1] = REGW * (rl / (float)B_N);
    }
}

extern "C" void kernel_launch(void* const* d_in, const int* in_sizes, int n_in,
                              void* d_out, int out_size, void* d_ws, size_t ws_size,
                              hipStream_t stream) {
    const float* clf     = (const float*)d_in[0];
    const float* reg     = (const float*)d_in[1];
    const float* anchors = (const float*)d_in[2];
    const float* ann     = (const float*)d_in[3];
    float* out = (float*)d_out;
    float* ws  = (float*)d_ws;

    // All ws slots are written unconditionally every launch -> no memset.
    {
        dim3 grid(MATCH_BX, B_N);
        match_kernel<<<grid, 256, 0, stream>>>(anchors, reg, ann, clf, ws);
    }
    {
        dim3 grid(BASE_BX, B_N);
        base_kernel<<<grid, 256, 0, stream>>>(clf, ws);
    }
    finalize_kernel<<<1, 256, 0, stream>>>(ws, out);
}

// Round 5
// 218.252 us; speedup vs baseline: 1.7958x; 1.0934x over previous
//
#include <hip/hip_runtime.h>

// FocalLoss (RetinaNet-style) on MI355X.
// Inputs (fp32): classifications (8,49104,90), regressions (8,49104,4),
//                anchors (1,49104,4), annotations (8,32,5)
// Output: 2 fp32 scalars (clf_loss, reg_loss).
//
// R5 (= R4 with compile fix): single fused pass. Each block owns 256 anchors
// of one image:
//   phase 1: IoU match vs 32 boxes (LDS) -> per-anchor state in LDS,
//            reg smooth-L1 partial (coalesced float4 reg read).
//   phase 2: stream the block's contiguous clf span (coalesced float4),
//            branch-free focal term selected by LDS state.
// clf read exactly once; no global atomics (R3 lesson); block partials to
// unique ws slots; tiny finalize kernel.

namespace {
constexpr int B_N = 8;
constexpr int A_N = 49104;
constexpr int C_N = 90;
constexpr int M_N = 32;
constexpr float EPSF   = 1e-4f;
constexpr float ACCEPT = 0.5f;
constexpr float REJECT = 0.4f;
constexpr float SL1R   = 9.0f;
constexpr float CLFW   = 1.0f;
constexpr float REGW   = 50.0f;

constexpr int APB     = 256;                      // anchors per block
constexpr int NBX     = (A_N + APB - 1) / APB;    // 192 blocks per image

__device__ __forceinline__ float clampx(float x) {
    return __builtin_amdgcn_fmed3f(x, EPSF, 1.0f - EPSF);
}
} // namespace

// ---------------- kernel 1: fused match + reg + clf focal ----------------
// grid (NBX, B), block 256.
__global__ void fused_kernel(const float* __restrict__ anchors,
                             const float* __restrict__ reg,
                             const float* __restrict__ ann,
                             const float* __restrict__ clf,
                             float4* __restrict__ part)   // [B][NBX] (cnt,rsum,csum,0)
{
    __shared__ float sann[M_N * 5];
    __shared__ int   sstate[APB];
    __shared__ float sred[4][3];

    const int b   = blockIdx.y;
    const int a0  = blockIdx.x * APB;
    const int tid = threadIdx.x;
    if (tid < M_N * 5) sann[tid] = ann[b * M_N * 5 + tid];
    __syncthreads();

    // ---------- phase 1: match ----------
    float cnt  = 0.0f;
    float rsum = 0.0f;
    int   s    = -2;              // default for out-of-range anchors: skip row
    const int i = a0 + tid;

    if (i < A_N) {
        const float4 av = ((const float4*)anchors)[i];
        const float ay1 = av.x, ax1 = av.y, ay2 = av.z, ax2 = av.w;
        const float aw = ax2 - ax1, ah = ay2 - ay1;
        const float aarea = aw * ah;

        float best = -3.4e38f;
        int   arg  = 0;
        #pragma unroll 8
        for (int j = 0; j < M_N; ++j) {
            const float bx1 = sann[j*5+0], by1 = sann[j*5+1];
            const float bx2 = sann[j*5+2], by2 = sann[j*5+3];
            const float lb  = sann[j*5+4];
            float iw = fminf(ax2, bx2) - fmaxf(ax1, bx1); iw = fmaxf(iw, 0.0f);
            float ih = fminf(ay2, by2) - fmaxf(ay1, by1); ih = fmaxf(ih, 0.0f);
            const float inter = iw * ih;
            const float barea = (bx2 - bx1) * (by2 - by1);
            const float uni   = fmaxf(aarea + barea - inter, 1e-8f);
            float iou = inter / uni;
            if (lb == -1.0f) iou = -1.0f;
            if (iou > best) { best = iou; arg = j; } // first-occurrence argmax
        }

        const bool matched   = best > ACCEPT;
        const bool unmatched = best < REJECT;

        if (matched) {
            s   = (int)sann[arg*5+4] - 1;   // class index 0..89
            cnt = 1.0f;
            const float bx1 = sann[arg*5+0], by1 = sann[arg*5+1];
            const float bx2 = sann[arg*5+2], by2 = sann[arg*5+3];
            const float gwr = bx2 - bx1, ghr = by2 - by1;
            const float gcx = bx1 + 0.5f * gwr, gcy = by1 + 0.5f * ghr;
            const float gw  = fmaxf(gwr, 1.0f), gh = fmaxf(ghr, 1.0f);
            const float acx = ax1 + 0.5f * aw, acy = ay1 + 0.5f * ah;
            const float t0 = (gcy - acy) / ah;
            const float t1 = (gcx - acx) / aw;
            const float t2 = __logf(gh / ah);
            const float t3 = __logf(gw / aw);
            const float4 rv = ((const float4*)reg)[b * A_N + i];
            float d;
            d = fabsf(SL1R * (rv.x - t0)); rsum += (d < 1.0f) ? 0.5f*d*d : d - 0.5f;
            d = fabsf(SL1R * (rv.y - t1)); rsum += (d < 1.0f) ? 0.5f*d*d : d - 0.5f;
            d = fabsf(SL1R * (rv.z - t2)); rsum += (d < 1.0f) ? 0.5f*d*d : d - 0.5f;
            d = fabsf(SL1R * (rv.w - t3)); rsum += (d < 1.0f) ? 0.5f*d*d : d - 0.5f;
        } else {
            s = unmatched ? -1 : -2;
        }
    }
    sstate[tid] = s;
    __syncthreads();

    // ---------- phase 2: stream this block's clf span ----------
    // span: anchors [a0, a0+nA), nA*90 floats, base 16B-aligned (a0*360 % 16 == 0)
    const int nA  = min(APB, A_N - a0);
    const int nF4 = nA * C_N / 4;                 // 5760 (full) or 4680 (last)
    const float4* __restrict__ p =
        (const float4*)(clf + ((size_t)b * A_N + a0) * C_N);

    float csum = 0.0f;

    auto term = [&](float x, int st, int c) -> float {
        const bool ispos = (st == c);
        x = clampx(x);
        const float y  = ispos ? x : 1.0f - x;
        float al = ispos ? -0.25f : -0.75f;       // sign folds the -log
        al = (st == -2) ? 0.0f : al;
        const float o = 1.0f - y;
        return al * o * o * __logf(y);
    };

    for (int f = tid; f < nF4; f += 256) {
        const float4 v = p[f];
        const int idx = 4 * f;
        const int a   = (int)((unsigned)idx / 90u);   // magic-mul
        const int c0  = idx - 90 * a;                 // even, 0..88
        const bool strad = (c0 == 88);                // elements 2,3 belong to a+1
        const int s0 = sstate[a];
        const int s1 = strad ? sstate[a + 1] : s0;    // a+1 in range: c0==88 => a <= nA-2
        const int c2 = strad ? 0 : c0 + 2;
        const int c3 = strad ? 1 : c0 + 3;
        csum += term(v.x, s0, c0);
        csum += term(v.y, s0, c0 + 1);
        csum += term(v.z, s1, c2);
        csum += term(v.w, s1, c3);
    }

    // ---------- block reduce, one ws write ----------
    #pragma unroll
    for (int off = 32; off > 0; off >>= 1) {
        cnt  += __shfl_down(cnt,  off);
        rsum += __shfl_down(rsum, off);
        csum += __shfl_down(csum, off);
    }
    const int wid = tid >> 6;
    if ((tid & 63) == 0) {
        sred[wid][0] = cnt; sred[wid][1] = rsum; sred[wid][2] = csum;
    }
    __syncthreads();
    if (tid == 0) {
        float c = 0.f, r = 0.f, k = 0.f;
        #pragma unroll
        for (int w = 0; w < 4; ++w) { c += sred[w][0]; r += sred[w][1]; k += sred[w][2]; }
        part[b * NBX + blockIdx.x] = make_float4(c, r, k, 0.0f);
    }
}

// ---------------- kernel 2: finalize ----------------
// 1 block, 256 threads: threads b*32..b*32+31 reduce image b's partials.
__global__ void finalize_kernel(const float4* __restrict__ part,
                                float*        __restrict__ out)
{
    __shared__ float s_cnt[B_N], s_rsum[B_N], s_csum[B_N];
    const int tid = threadIdx.x;
    const int b   = tid >> 5;
    const int j   = tid & 31;

    float cnt = 0.f, rsum = 0.f, csum = 0.f;
    #pragma unroll
    for (int k = 0; k < NBX / 32; ++k) {            // 6 slots
        const float4 m = part[b * NBX + j + 32 * k];
        cnt += m.x; rsum += m.y; csum += m.z;
    }
    #pragma unroll
    for (int off = 16; off > 0; off >>= 1) {
        cnt  += __shfl_down(cnt,  off, 32);
        rsum += __shfl_down(rsum, off, 32);
        csum += __shfl_down(csum, off, 32);
    }
    if (j == 0) { s_cnt[b] = cnt; s_rsum[b] = rsum; s_csum[b] = csum; }
    __syncthreads();
    if (tid == 0) {
        float cl = 0.0f, rl = 0.0f;
        #pragma unroll
        for (int bb = 0; bb < B_N; ++bb) {
            const float n = s_cnt[bb];
            cl += s_csum[bb] / fmaxf(1.0f, n);
            if (n > 0.0f) rl += s_rsum[bb] / (4.0f * n);
        }
        out[0] = CLFW * (cl / (float)B_N);
        out[1] = REGW * (rl / (float)B_N);
    }
}

extern "C" void kernel_launch(void* const* d_in, const int* in_sizes, int n_in,
                              void* d_out, int out_size, void* d_ws, size_t ws_size,
                              hipStream_t stream) {
    const float* clf     = (const float*)d_in[0];
    const float* reg     = (const float*)d_in[1];
    const float* anchors = (const float*)d_in[2];
    const float* ann     = (const float*)d_in[3];
    float*  out  = (float*)d_out;
    float4* part = (float4*)d_ws;   // [B][NBX], every slot written each launch

    {
        dim3 grid(NBX, B_N);
        fused_kernel<<<grid, 256, 0, stream>>>(anchors, reg, ann, clf, part);
    }
    finalize_kernel<<<1, 256, 0, stream>>>(part, out);
}

// Round 6
// 215.185 us; speedup vs baseline: 1.8214x; 1.0143x over previous
//
#include <hip/hip_runtime.h>

// FocalLoss (RetinaNet-style) on MI355X.
// Inputs (fp32): classifications (8,49104,90), regressions (8,49104,4),
//                anchors (1,49104,4), annotations (8,32,5)
// Output: 2 fp32 scalars (clf_loss, reg_loss).
//
// R6: fused kernel, but the clf stream is now UNCONDITIONAL (no per-element
// state): sum x^2*log2(1-x) over everything with 4 loads in flight/thread.
// Matched/ignored anchors go to a compact LDS worklist in phase 1; sparse
// corrections (pos-neg for the matched element, -row-sum for ignored rows)
// are applied from L2-hot re-reads. No global atomics (R3 lesson); block
// partials to unique ws slots.

namespace {
constexpr int B_N = 8;
constexpr int A_N = 49104;
constexpr int C_N = 90;
constexpr int M_N = 32;
constexpr float EPSF   = 1e-4f;
constexpr float ACCEPT = 0.5f;
constexpr float REJECT = 0.4f;
constexpr float SL1R   = 9.0f;
constexpr float CLFW   = 1.0f;
constexpr float REGW   = 50.0f;
constexpr float LN2    = 0.69314718055994530942f;

constexpr int APB = 256;                      // anchors per block
constexpr int NBX = (A_N + APB - 1) / APB;    // 192 blocks per image

__device__ __forceinline__ float clampx(float x) {
    return __builtin_amdgcn_fmed3f(x, EPSF, 1.0f - EPSF);
}
__device__ __forceinline__ float neg_term(float x) {   // tgt==0 focal term (ln)
    x = clampx(x);
    return 0.75f * x * x * (-__logf(1.0f - x));
}
__device__ __forceinline__ float pos_term(float x) {   // tgt==1 focal term (ln)
    x = clampx(x);
    float o = 1.0f - x;
    return 0.25f * o * o * (-__logf(x));
}
} // namespace

// ---------------- kernel 1: fused match + reg + clf focal ----------------
// grid (NBX, B), block 256.
__global__ void fused_kernel(const float* __restrict__ anchors,
                             const float* __restrict__ reg,
                             const float* __restrict__ ann,
                             const float* __restrict__ clf,
                             float4* __restrict__ part)  // [B][NBX] (cnt,rsum,S,corr)
{
    __shared__ float sann[M_N * 5];
    __shared__ int   s_match[APB];   // (local_a << 8) | class
    __shared__ int   s_ign[APB];     // local_a
    __shared__ int   s_nm, s_ni;
    __shared__ float sred[4][4];

    const int b   = blockIdx.y;
    const int a0  = blockIdx.x * APB;
    const int tid = threadIdx.x;
    if (tid < M_N * 5) sann[tid] = ann[b * M_N * 5 + tid];
    if (tid == 0) { s_nm = 0; s_ni = 0; }
    __syncthreads();

    // ---------- phase 1: match ----------
    float cnt  = 0.0f;
    float rsum = 0.0f;
    float corr = 0.0f;
    const int i = a0 + tid;

    if (i < A_N) {
        const float4 av = ((const float4*)anchors)[i];
        const float ay1 = av.x, ax1 = av.y, ay2 = av.z, ax2 = av.w;
        const float aw = ax2 - ax1, ah = ay2 - ay1;
        const float aarea = aw * ah;

        float best = -3.4e38f;
        int   arg  = 0;
        #pragma unroll 8
        for (int j = 0; j < M_N; ++j) {
            const float bx1 = sann[j*5+0], by1 = sann[j*5+1];
            const float bx2 = sann[j*5+2], by2 = sann[j*5+3];
            const float lb  = sann[j*5+4];
            float iw = fminf(ax2, bx2) - fmaxf(ax1, bx1); iw = fmaxf(iw, 0.0f);
            float ih = fminf(ay2, by2) - fmaxf(ay1, by1); ih = fmaxf(ih, 0.0f);
            const float inter = iw * ih;
            const float barea = (bx2 - bx1) * (by2 - by1);
            const float uni   = fmaxf(aarea + barea - inter, 1e-8f);
            float iou = inter / uni;
            if (lb == -1.0f) iou = -1.0f;
            if (iou > best) { best = iou; arg = j; } // first-occurrence argmax
        }

        const bool matched   = best > ACCEPT;
        const bool unmatched = best < REJECT;

        if (matched) {
            const int s = (int)sann[arg*5+4] - 1;   // class 0..89
            cnt = 1.0f;
            const int slot = atomicAdd(&s_nm, 1);
            s_match[slot] = (tid << 8) | s;
            // regression loss
            const float bx1 = sann[arg*5+0], by1 = sann[arg*5+1];
            const float bx2 = sann[arg*5+2], by2 = sann[arg*5+3];
            const float gwr = bx2 - bx1, ghr = by2 - by1;
            const float gcx = bx1 + 0.5f * gwr, gcy = by1 + 0.5f * ghr;
            const float gw  = fmaxf(gwr, 1.0f), gh = fmaxf(ghr, 1.0f);
            const float acx = ax1 + 0.5f * aw, acy = ay1 + 0.5f * ah;
            const float t0 = (gcy - acy) / ah;
            const float t1 = (gcx - acx) / aw;
            const float t2 = __logf(gh / ah);
            const float t3 = __logf(gw / aw);
            const float4 rv = ((const float4*)reg)[b * A_N + i];
            float d;
            d = fabsf(SL1R * (rv.x - t0)); rsum += (d < 1.0f) ? 0.5f*d*d : d - 0.5f;
            d = fabsf(SL1R * (rv.y - t1)); rsum += (d < 1.0f) ? 0.5f*d*d : d - 0.5f;
            d = fabsf(SL1R * (rv.z - t2)); rsum += (d < 1.0f) ? 0.5f*d*d : d - 0.5f;
            d = fabsf(SL1R * (rv.w - t3)); rsum += (d < 1.0f) ? 0.5f*d*d : d - 0.5f;
        } else if (!unmatched) {
            const int slot = atomicAdd(&s_ni, 1);
            s_ign[slot] = tid;
        }
    }
    __syncthreads();

    // ---------- phase 2: unconditional base stream ----------
    // S = sum over span of x^2 * log2(1-x); scaled by -0.75*ln2 in finalize.
    const int nA  = min(APB, A_N - a0);
    const int nF4 = nA * C_N / 4;                 // 5760 full, 4680 last
    const float4* __restrict__ p =
        (const float4*)(clf + ((size_t)b * A_N + a0) * C_N);

    float S = 0.0f;

    auto w4 = [](float4 v) -> float {
        float s = 0.0f;
        const float x0 = clampx(v.x), x1 = clampx(v.y);
        const float x2 = clampx(v.z), x3 = clampx(v.w);
        s = fmaf(x0 * x0, __log2f(1.0f - x0), s);
        s = fmaf(x1 * x1, __log2f(1.0f - x1), s);
        s = fmaf(x2 * x2, __log2f(1.0f - x2), s);
        s = fmaf(x3 * x3, __log2f(1.0f - x3), s);
        return s;
    };

    int f = tid;
    #pragma unroll 1
    for (; f + 768 < nF4; f += 1024) {            // 4 independent loads in flight
        const float4 v0 = p[f];
        const float4 v1 = p[f + 256];
        const float4 v2 = p[f + 512];
        const float4 v3 = p[f + 768];
        S += w4(v0) + w4(v1) + w4(v2) + w4(v3);
    }
    for (; f < nF4; f += 256) S += w4(p[f]);

    // ---------- phase 3: sparse corrections (rows are L1/L2-hot) ----------
    const int nm = s_nm, ni = s_ni;
    for (int k = tid; k < nm; k += 256) {
        const int packed = s_match[k];
        const int a  = packed >> 8;
        const int sc = packed & 0xFF;
        const float x = clf[((size_t)b * A_N + a0 + a) * C_N + sc];
        corr += pos_term(x) - neg_term(x);
    }
    const int wid  = tid >> 6;
    const int lane = tid & 63;
    for (int e = wid; e < ni; e += 4) {           // one wave per ignored row
        const int a = s_ign[e];
        const float2* __restrict__ r2 =
            (const float2*)(clf + ((size_t)b * A_N + a0 + a) * C_N);
        if (lane < 45) {                          // 45 lanes x float2 = 90 elems
            const float2 u = r2[lane];
            corr -= neg_term(u.x) + neg_term(u.y);
        }
    }

    // ---------- block reduce, one ws write ----------
    #pragma unroll
    for (int off = 32; off > 0; off >>= 1) {
        cnt  += __shfl_down(cnt,  off);
        rsum += __shfl_down(rsum, off);
        S    += __shfl_down(S,    off);
        corr += __shfl_down(corr, off);
    }
    if (lane == 0) {
        sred[wid][0] = cnt; sred[wid][1] = rsum;
        sred[wid][2] = S;   sred[wid][3] = corr;
    }
    __syncthreads();
    if (tid == 0) {
        float c = 0.f, r = 0.f, ss = 0.f, k = 0.f;
        #pragma unroll
        for (int w = 0; w < 4; ++w) {
            c += sred[w][0]; r += sred[w][1]; ss += sred[w][2]; k += sred[w][3];
        }
        part[b * NBX + blockIdx.x] = make_float4(c, r, ss, k);
    }
}

// ---------------- kernel 2: finalize ----------------
// 1 block, 256 threads: threads b*32..b*32+31 reduce image b's partials.
__global__ void finalize_kernel(const float4* __restrict__ part,
                                float*        __restrict__ out)
{
    __shared__ float s_cnt[B_N], s_rsum[B_N], s_S[B_N], s_corr[B_N];
    const int tid = threadIdx.x;
    const int b   = tid >> 5;
    const int j   = tid & 31;

    float cnt = 0.f, rsum = 0.f, S = 0.f, corr = 0.f;
    #pragma unroll
    for (int k = 0; k < NBX / 32; ++k) {            // 6 slots
        const float4 m = part[b * NBX + j + 32 * k];
        cnt += m.x; rsum += m.y; S += m.z; corr += m.w;
    }
    #pragma unroll
    for (int off = 16; off > 0; off >>= 1) {
        cnt  += __shfl_down(cnt,  off, 32);
        rsum += __shfl_down(rsum, off, 32);
        S    += __shfl_down(S,    off, 32);
        corr += __shfl_down(corr, off, 32);
    }
    if (j == 0) { s_cnt[b] = cnt; s_rsum[b] = rsum; s_S[b] = S; s_corr[b] = corr; }
    __syncthreads();
    if (tid == 0) {
        float cl = 0.0f, rl = 0.0f;
        #pragma unroll
        for (int bb = 0; bb < B_N; ++bb) {
            const float n = s_cnt[bb];
            const float clf_total = -0.75f * LN2 * s_S[bb] + s_corr[bb];
            cl += clf_total / fmaxf(1.0f, n);
            if (n > 0.0f) rl += s_rsum[bb] / (4.0f * n);
        }
        out[0] = CLFW * (cl / (float)B_N);
        out[1] = REGW * (rl / (float)B_N);
    }
}

extern "C" void kernel_launch(void* const* d_in, const int* in_sizes, int n_in,
                              void* d_out, int out_size, void* d_ws, size_t ws_size,
                              hipStream_t stream) {
    const float* clf     = (const float*)d_in[0];
    const float* reg     = (const float*)d_in[1];
    const float* anchors = (const float*)d_in[2];
    const float* ann     = (const float*)d_in[3];
    float*  out  = (float*)d_out;
    float4* part = (float4*)d_ws;   // [B][NBX], every slot written each launch

    {
        dim3 grid(NBX, B_N);
        fused_kernel<<<grid, 256, 0, stream>>>(anchors, reg, ann, clf, part);
    }
    finalize_kernel<<<1, 256, 0, stream>>>(part, out);
}